// Round 19
// baseline (194.775 us; speedup 1.0000x reference)
//
#include <hip/hip_runtime.h>
#include <math.h>

typedef int v4i __attribute__((ext_vector_type(4)));
typedef int v16i __attribute__((ext_vector_type(16)));
typedef unsigned long long u64;

#define Bn 32
#define Cc 256
#define Hh 56
#define Ww 56
#define RSTR (34 * 256)      // LDS bytes per act row: 34 cols x 256 u8 channels
#define ACT_LDS (5 * RSTR)   // 43520 ; x3 blocks = 130560 <= 160 KiB
#define NSTG (5 * 34 * 16)   // 2720 packed u64 staged per block

// ---------------- block-wide sum over 256 threads ----------------
__device__ __forceinline__ float block_sum(float v, float* red) {
#pragma unroll
    for (int off = 32; off > 0; off >>= 1) v += __shfl_down(v, off, 64);
    const int wv = threadIdx.x >> 6;
    __syncthreads();
    if ((threadIdx.x & 63) == 0) red[wv] = v;
    __syncthreads();
    return red[0] + red[1] + red[2] + red[3];
}

// ---- IR-Net binarize + pack sign codes, BOTH layers in one launch ----
// blockIdx 0..255 -> layer 1; 256..511 -> layer 2.
// v4i unit index: ((tap*8 + c32)*8 + octile)*64 + lane ; lane=(half<<5)|(oc&31)
__global__ __launch_bounds__(256) void k_binpack2(const float* __restrict__ w1,
                                                  const float* __restrict__ w2,
                                                  signed char* __restrict__ wf1,
                                                  signed char* __restrict__ wf2,
                                                  float* __restrict__ wsc1,
                                                  float* __restrict__ wsc2) {
    __shared__ float red[4];
    const int lay = blockIdx.x >> 8;
    const int o = blockIdx.x & 255;
    const float* w = lay ? w2 : w1;
    signed char* wf = lay ? wf2 : wf1;
    float* wsc = lay ? wsc2 : wsc1;
    const float* wo = w + (size_t)o * 2304;
    const int t = threadIdx.x;
    float v[9];
    float s = 0.f, s2 = 0.f;
#pragma unroll
    for (int i = 0; i < 9; ++i) {
        v[i] = wo[t * 9 + i];
        s += v[i];
        s2 += v[i] * v[i];
    }
    s = block_sum(s, red);
    s2 = block_sum(s2, red);
    const float mu = s * (1.f / 2304.f);
    const float sd = sqrtf(fmaxf(s2 * (1.f / 2304.f) - mu * mu, 0.f));
    float sa = 0.f;
#pragma unroll
    for (int i = 0; i < 9; ++i) sa += fabsf(v[i] - mu);
    sa = block_sum(sa, red);
    if (t == 0) wsc[o] = (sa * (1.f / 2304.f)) / (sd + 1e-5f);
    const int c = t, c32 = c >> 5, hf = (c >> 4) & 1, j = c & 15;
    const int lane = (hf << 5) | (o & 31), octile = o >> 5;
#pragma unroll
    for (int tap = 0; tap < 9; ++tap) {
        const float d = v[tap] - mu;
        const signed char sg = (d > 0.f) ? 1 : ((d < 0.f) ? -1 : 0);
        wf[(size_t)(((tap * 8 + c32) * 8 + octile) * 64 + lane) * 16 + j] = sg;
    }
}

// ---- epilogue params: ep = [f1(256), beta1(256), f2(256), beta2(256)] ----
__global__ void k_prep(const float* __restrict__ g1, const float* __restrict__ b1,
                       const float* __restrict__ m1, const float* __restrict__ v1,
                       const float* __restrict__ g2, const float* __restrict__ b2,
                       const float* __restrict__ m2, const float* __restrict__ v2,
                       const float* __restrict__ a1p, const float* __restrict__ a2p,
                       const float* __restrict__ ws1, const float* __restrict__ ws2,
                       float* __restrict__ ep) {
    const int i = threadIdx.x;
    const float i1 = g1[i] / sqrtf(v1[i] + 1e-5f);
    const float i2 = g2[i] / sqrtf(v2[i] + 1e-5f);
    ep[i] = a1p[0] * ws1[i] * i1;
    ep[256 + i] = b1[i] - m1[i] * i1;
    ep[512 + i] = a2p[0] * ws2[i] * i2;
    ep[768 + i] = b2[i] - m2[i] * i2;
}

// ---- LSQ 4-bit quantize NCHW fp32 -> nibble-packed NHWC ----
// per (n,h,w): 128B = 16 groups x 8B; group g8 byte k = q[g8*16+k] | q[g8*16+k+8]<<4
__global__ __launch_bounds__(256) void k_quant_nhwc(const float* __restrict__ x,
                                                    unsigned char* __restrict__ xq,
                                                    const float* __restrict__ ap) {
    __shared__ unsigned char q[3584];  // [w 56][c 64], dword-swizzled
    const int bid = blockIdx.x;
    const int cg = bid & 3;
    const int h = (bid >> 2) % Hh;
    const int n = bid / (4 * Hh);
    const float a = ap[0];
    const int c0 = cg * 64;
    for (int i = threadIdx.x; i < 3584; i += 256) {
        const int cl = i / 56;
        const int w = i - cl * 56;
        const float v = x[(((size_t)n * Cc + c0 + cl) * Hh + h) * Ww + w];
        const float xs = fminf(fmaxf(v / a, 0.f), 15.f);
        q[w * 64 + (((cl >> 2) ^ (w & 15)) << 2) + (cl & 3)] = (unsigned char)(int)rintf(xs);
    }
    __syncthreads();
    const unsigned int* q32 = (const unsigned int*)q;
    unsigned int* dst = (unsigned int*)xq + ((size_t)(n * Hh + h) * Ww) * 32;
    for (int j = threadIdx.x; j < 448; j += 256) {
        const int w = j >> 3, g8l = (j >> 1) & 3, hf = j & 1;
        const unsigned int lo = q32[w * 16 + ((g8l * 4 + hf) ^ (w & 15))];
        const unsigned int hi = q32[w * 16 + ((g8l * 4 + 2 + hf) ^ (w & 15))];
        dst[w * 32 + (cg * 4 + g8l) * 2 + hf] = lo | (hi << 4);
    }
}

// ---- implicit-GEMM conv, i8 MFMA 32x32x32, 2 octiles/wave x rows=3 ----
// grid 1216 = 32n x 19hb x 2mh ; block 256 thr = 4 waves = 256 oc x 32 m x 3 r
// wave g: oc [g*64, +64) (octiles 2g,2g+1) x 3 rows x 32 cols
// acc = 2x3 v16i = 96 AGPR, ~72 VGPR -> 3 waves/SIMD (the duty-law optimum:
// util = 36.6*MFMA/(ops*400)*waves: o2r3@3w = 45% vs all previous cells ~36%).
// LDS 43.5KB -> 3 blocks/CU. hb=18 block handles rows 54,55 (row 56 masked).
template <bool QOUT>
__global__ __launch_bounds__(256, 3) void k_conv(const unsigned char* __restrict__ xin,
                                                 const signed char* __restrict__ wf,
                                                 const float* __restrict__ ep,
                                                 const float* __restrict__ a2p,
                                                 unsigned char* __restrict__ hq,
                                                 float* __restrict__ yout) {
    __shared__ __align__(16) unsigned char sm[ACT_LDS];  // acts; hbuf aliased later
    const int bid = blockIdx.x;
    const int mh = bid & 1;
    const int hb = (bid >> 1) % 19;
    const int n = (bid >> 1) / 19;
    const int h0 = hb * 3;
    const int mbase = mh * 32;
    const int tid = threadIdx.x;

    // ---- stage 5 act rows x 34 cols: packed global -> UNPACKED u8 LDS ----
    {
        u64 tmp[11];
#pragma unroll
        for (int k = 0; k < 11; ++k) {
            int u = tid + (k << 8);
            u = u > (NSTG - 1) ? (NSTG - 1) : u;
            const int r = u / 544;
            const int rem = u - r * 544;
            const int col = rem >> 4;
            const int t8 = rem & 15;
            int y = h0 - 1 + r;
            int xi = mbase - 1 + col;
            y = y < 0 ? 0 : (y > 55 ? 55 : y);
            xi = xi < 0 ? 0 : (xi > 55 ? 55 : xi);
            tmp[k] = *(const u64*)(xin + ((((size_t)n * Hh + y) * Ww + xi) << 7) + (t8 << 3));
        }
#pragma unroll
        for (int k = 0; k < 11; ++k) {
            const int u = tid + (k << 8);
            if (u < NSTG) {
                const int r = u / 544;
                const int rem = u - r * 544;
                const int col = rem >> 4;
                const int t8 = rem & 15;
                const int y = h0 - 1 + r;
                const int xi = mbase - 1 + col;
                const u64 p = ((unsigned)y < 56u && (unsigned)xi < 56u) ? tmp[k] : 0;
                const u64 lo = p & 0x0F0F0F0F0F0F0F0FULL;
                const u64 hi = (p >> 4) & 0x0F0F0F0F0F0F0F0FULL;
                v4i wv;
                wv[0] = (int)lo;
                wv[1] = (int)(lo >> 32);
                wv[2] = (int)hi;
                wv[3] = (int)(hi >> 32);
                *(v4i*)(sm + r * RSTR + col * 256 + ((t8 ^ (col & 15)) << 4)) = wv;
            }
        }
    }
    __syncthreads();

    const int lane = tid & 63;
    const int g = tid >> 6;
    const int half = lane >> 5;
    const int lm = lane & 31;
    const int boff = ((bid << 2) | g) & 7;  // per-wave c32 stagger (integer-exact)

    v16i acc[2][3] = {};
    const v4i* wpg = (const v4i*)wf + (2 * g) * 64 + lane;

    int pkw[3];
#pragma unroll
    for (int kw = 0; kw < 3; ++kw) {
        const int col = lm + kw;  // 0..33, in range
        pkw[kw] = (col * 256) ^ (half << 4) ^ ((col & 15) << 4);
    }

#pragma unroll 1
    for (int ii = 0; ii < 8; ++ii) {
        const int c32 = (ii + boff) & 7;
        const int cs = c32 << 5;
#pragma unroll
        for (int kw = 0; kw < 3; ++kw) {
            const unsigned char* bp = sm + (pkw[kw] ^ cs);
            v4i bfr[5];
#pragma unroll
            for (int ar = 0; ar < 5; ++ar)
                bfr[ar] = *(const v4i*)(bp + ar * RSTR);
            v4i aw0[3], aw1[3];
#pragma unroll
            for (int kh = 0; kh < 3; ++kh) {
                const int idx = ((kh * 3 + kw) * 8 + c32) << 9;
                aw0[kh] = wpg[idx];
                aw1[kh] = wpg[idx + 64];
            }
            __builtin_amdgcn_s_setprio(1);
#pragma unroll
            for (int kh = 0; kh < 3; ++kh)
#pragma unroll
                for (int r = 0; r < 3; ++r) {
                    acc[0][r] = __builtin_amdgcn_mfma_i32_32x32x32_i8(aw0[kh], bfr[r + kh],
                                                                      acc[0][r], 0, 0, 0);
                    acc[1][r] = __builtin_amdgcn_mfma_i32_32x32x32_i8(aw1[kh], bfr[r + kh],
                                                                      acc[1][r], 0, 0, 0);
                }
            __builtin_amdgcn_s_setprio(0);
        }
    }

    // ---- epilogue ----
    if constexpr (QOUT) {
        __syncthreads();  // acts dead; reuse sm as hbuf [3 r][32 w][32 dwords]
        unsigned int* hb = (unsigned int*)sm;
        const float inva = 1.0f / a2p[0];
#pragma unroll
        for (int oct = 0; oct < 2; ++oct) {
            const int ocb = g * 64 + oct * 32;
            const int d0 = 8 * g + 4 * oct + half;
#pragma unroll
            for (int r = 0; r < 3; ++r) {
                const v16i av = acc[oct][r];
                unsigned int pk0 = 0, pk1 = 0;
#pragma unroll
                for (int q = 0; q < 4; ++q) {
                    const int oc = ocb + 4 * half + q;
                    const unsigned int c0 = (unsigned int)(int)rintf(
                        fminf(fmaxf(fmaf((float)av[q], ep[oc], ep[256 + oc]), 0.f) * inva, 15.f));
                    const unsigned int c1 = (unsigned int)(int)rintf(
                        fminf(fmaxf(fmaf((float)av[4 + q], ep[oc + 8], ep[264 + oc]), 0.f) * inva, 15.f));
                    const unsigned int c2 = (unsigned int)(int)rintf(
                        fminf(fmaxf(fmaf((float)av[8 + q], ep[oc + 16], ep[272 + oc]), 0.f) * inva, 15.f));
                    const unsigned int c3 = (unsigned int)(int)rintf(
                        fminf(fmaxf(fmaf((float)av[12 + q], ep[oc + 24], ep[280 + oc]), 0.f) * inva, 15.f));
                    pk0 |= (c0 | (c1 << 4)) << (8 * q);
                    pk1 |= (c2 | (c3 << 4)) << (8 * q);
                }
                const int rb = (r * 32 + lm) * 32;
                hb[rb + (d0 ^ lm)] = pk0;
                hb[rb + ((d0 + 2) ^ lm)] = pk1;
            }
        }
        __syncthreads();
        unsigned int* dst = (unsigned int*)hq;
        for (int j = tid; j < 3 * 32 * 32; j += 256) {
            const int dw = j & 31;
            const int wl = (j >> 5) & 31;
            const int r = j >> 10;
            const int w = mbase + wl;
            const int h = h0 + r;
            if (w < 56 && h < 56)
                dst[((size_t)((n * Hh + h) * Ww) + w) * 32 + dw] =
                    hb[((r * 32 + wl) << 5) + (dw ^ wl)];
        }
    } else {
        const int w = mbase + lm;
        if (w < 56) {
            float* dst = yout + (size_t)n * Cc * 3136 + (size_t)h0 * 56 + w;
#pragma unroll
            for (int oct = 0; oct < 2; ++oct)
#pragma unroll
                for (int r = 0; r < 3; ++r) {
                    if (h0 + r < 56) {
                        const v16i av = acc[oct][r];
#pragma unroll
                        for (int reg = 0; reg < 16; ++reg) {
                            const int oc = g * 64 + oct * 32 + (reg & 3) + 8 * (reg >> 2) + 4 * half;
                            dst[(size_t)oc * 3136 + r * 56] =
                                fmaxf(fmaf((float)av[reg], ep[oc], ep[256 + oc]), 0.f);
                        }
                    }
                }
        }
    }
}

extern "C" void kernel_launch(void* const* d_in, const int* in_sizes, int n_in,
                              void* d_out, int out_size, void* d_ws, size_t ws_size,
                              hipStream_t stream) {
    const float* x = (const float*)d_in[0];
    const float* w1 = (const float*)d_in[1];
    const float* a1 = (const float*)d_in[2];
    const float* g1 = (const float*)d_in[3];
    const float* b1 = (const float*)d_in[4];
    const float* m1 = (const float*)d_in[5];
    const float* v1 = (const float*)d_in[6];
    const float* w2 = (const float*)d_in[7];
    const float* a2 = (const float*)d_in[8];
    const float* g2 = (const float*)d_in[9];
    const float* b2 = (const float*)d_in[10];
    const float* m2 = (const float*)d_in[11];
    const float* v2 = (const float*)d_in[12];

    // workspace (~27.1 MB)
    signed char* wf1 = (signed char*)d_ws;             // 589824 B
    signed char* wf2 = wf1 + 589824;                   // 589824 B
    float* wsc1 = (float*)(wf2 + 589824);              // 256 f
    float* wsc2 = wsc1 + 256;                          // 256 f
    float* ep = wsc2 + 256;                            // 1024 f
    unsigned char* xq1 = (unsigned char*)(ep + 1024);  // 12845056 B (packed NHWC)
    unsigned char* hq = xq1 + (size_t)12845056;        // 12845056 B (packed NHWC)

    k_binpack2<<<512, 256, 0, stream>>>(w1, w2, wf1, wf2, wsc1, wsc2);
    k_prep<<<1, 256, 0, stream>>>(g1, b1, m1, v1, g2, b2, m2, v2, a1, a2, wsc1, wsc2, ep);
    k_quant_nhwc<<<Bn * Hh * 4, 256, 0, stream>>>(x, xq1, a1);

    // layer 1: packed x -> packed h (BN+ReLU+LSQ(alpha2) fused)
    k_conv<true><<<1216, 256, 0, stream>>>(xq1, wf1, ep, a2, hq, nullptr);
    // layer 2: packed h -> fp32 NCHW out (BN+ReLU)
    k_conv<false><<<1216, 256, 0, stream>>>(hq, wf2, ep + 512, nullptr, nullptr, (float*)d_out);
}

// Round 20
// 171.072 us; speedup vs baseline: 1.1386x; 1.1386x over previous
//
#include <hip/hip_runtime.h>
#include <math.h>

typedef int v4i __attribute__((ext_vector_type(4)));
typedef int v16i __attribute__((ext_vector_type(16)));
typedef unsigned long long u64;

#define Bn 32
#define Cc 256
#define Hh 56
#define Ww 56
#define RSTR (34 * 256)      // LDS bytes per act row: 34 cols x 256 u8 channels
#define ACT_LDS (6 * RSTR)   // 52224 ; x3 blocks = 156672 <= 160 KiB
#define NSTG (6 * 34 * 16)   // 3264 packed u64 staged per block

// ---------------- block-wide sum over 256 threads ----------------
__device__ __forceinline__ float block_sum(float v, float* red) {
#pragma unroll
    for (int off = 32; off > 0; off >>= 1) v += __shfl_down(v, off, 64);
    const int wv = threadIdx.x >> 6;
    __syncthreads();
    if ((threadIdx.x & 63) == 0) red[wv] = v;
    __syncthreads();
    return red[0] + red[1] + red[2] + red[3];
}

// ---- IR-Net binarize + pack sign codes, BOTH layers in one launch ----
// blockIdx 0..255 -> layer 1 (w1->wf1,wsc1); 256..511 -> layer 2.
// v4i unit index: ((tap*8 + c32)*8 + octile)*64 + lane ; lane=(half<<5)|(oc&31)
__global__ __launch_bounds__(256) void k_binpack2(const float* __restrict__ w1,
                                                  const float* __restrict__ w2,
                                                  signed char* __restrict__ wf1,
                                                  signed char* __restrict__ wf2,
                                                  float* __restrict__ wsc1,
                                                  float* __restrict__ wsc2) {
    __shared__ float red[4];
    const int lay = blockIdx.x >> 8;
    const int o = blockIdx.x & 255;
    const float* w = lay ? w2 : w1;
    signed char* wf = lay ? wf2 : wf1;
    float* wsc = lay ? wsc2 : wsc1;
    const float* wo = w + (size_t)o * 2304;
    const int t = threadIdx.x;
    float v[9];
    float s = 0.f, s2 = 0.f;
#pragma unroll
    for (int i = 0; i < 9; ++i) {
        v[i] = wo[t * 9 + i];
        s += v[i];
        s2 += v[i] * v[i];
    }
    s = block_sum(s, red);
    s2 = block_sum(s2, red);
    const float mu = s * (1.f / 2304.f);
    const float sd = sqrtf(fmaxf(s2 * (1.f / 2304.f) - mu * mu, 0.f));
    float sa = 0.f;
#pragma unroll
    for (int i = 0; i < 9; ++i) sa += fabsf(v[i] - mu);
    sa = block_sum(sa, red);
    if (t == 0) wsc[o] = (sa * (1.f / 2304.f)) / (sd + 1e-5f);
    const int c = t, c32 = c >> 5, hf = (c >> 4) & 1, j = c & 15;
    const int lane = (hf << 5) | (o & 31), octile = o >> 5;
#pragma unroll
    for (int tap = 0; tap < 9; ++tap) {
        const float d = v[tap] - mu;
        const signed char sg = (d > 0.f) ? 1 : ((d < 0.f) ? -1 : 0);
        wf[(size_t)(((tap * 8 + c32) * 8 + octile) * 64 + lane) * 16 + j] = sg;
    }
}

// ---- epilogue params: ep = [f1(256), beta1(256), f2(256), beta2(256)] ----
__global__ void k_prep(const float* __restrict__ g1, const float* __restrict__ b1,
                       const float* __restrict__ m1, const float* __restrict__ v1,
                       const float* __restrict__ g2, const float* __restrict__ b2,
                       const float* __restrict__ m2, const float* __restrict__ v2,
                       const float* __restrict__ a1p, const float* __restrict__ a2p,
                       const float* __restrict__ ws1, const float* __restrict__ ws2,
                       float* __restrict__ ep) {
    const int i = threadIdx.x;
    const float i1 = g1[i] / sqrtf(v1[i] + 1e-5f);
    const float i2 = g2[i] / sqrtf(v2[i] + 1e-5f);
    ep[i] = a1p[0] * ws1[i] * i1;
    ep[256 + i] = b1[i] - m1[i] * i1;
    ep[512 + i] = a2p[0] * ws2[i] * i2;
    ep[768 + i] = b2[i] - m2[i] * i2;
}

// ---- LSQ 4-bit quantize NCHW fp32 -> nibble-packed NHWC ----
// per (n,h,w): 128B = 16 groups x 8B; group g8 byte k = q[g8*16+k] | q[g8*16+k+8]<<4
__global__ __launch_bounds__(256) void k_quant_nhwc(const float* __restrict__ x,
                                                    unsigned char* __restrict__ xq,
                                                    const float* __restrict__ ap) {
    __shared__ unsigned char q[3584];  // [w 56][c 64], dword-swizzled
    const int bid = blockIdx.x;
    const int cg = bid & 3;
    const int h = (bid >> 2) % Hh;
    const int n = bid / (4 * Hh);
    const float a = ap[0];
    const int c0 = cg * 64;
    for (int i = threadIdx.x; i < 3584; i += 256) {
        const int cl = i / 56;
        const int w = i - cl * 56;
        const float v = x[(((size_t)n * Cc + c0 + cl) * Hh + h) * Ww + w];
        const float xs = fminf(fmaxf(v / a, 0.f), 15.f);
        q[w * 64 + (((cl >> 2) ^ (w & 15)) << 2) + (cl & 3)] = (unsigned char)(int)rintf(xs);
    }
    __syncthreads();
    const unsigned int* q32 = (const unsigned int*)q;
    unsigned int* dst = (unsigned int*)xq + ((size_t)(n * Hh + h) * Ww) * 32;
    for (int j = threadIdx.x; j < 448; j += 256) {
        const int w = j >> 3, g8l = (j >> 1) & 3, hf = j & 1;
        const unsigned int lo = q32[w * 16 + ((g8l * 4 + hf) ^ (w & 15))];
        const unsigned int hi = q32[w * 16 + ((g8l * 4 + 2 + hf) ^ (w & 15))];
        dst[w * 32 + (cg * 4 + g8l) * 2 + hf] = lo | (hi << 4);
    }
}

// ---- software-pipelined inner-loop macros (all indices compile-time) ----
#define LDA(AW, KW, C32)                                                   \
    do {                                                                   \
        _Pragma("unroll") for (int kh_ = 0; kh_ < 3; ++kh_)                \
            AW[kh_] = wpg[((kh_ * 3 + (KW)) * 8 + (C32)) << 9];            \
    } while (0)

#define LDB(BB, KW, C32)                                                   \
    do {                                                                   \
        const unsigned char* bp_ = sm + (pkw[(KW)] ^ ((C32) << 5));        \
        _Pragma("unroll") for (int ar_ = 0; ar_ < 6; ++ar_)                \
            BB[ar_] = *(const v4i*)(bp_ + ar_ * RSTR);                     \
    } while (0)

#define MM(AW, BB)                                                         \
    do {                                                                   \
        __builtin_amdgcn_s_setprio(1);                                     \
        _Pragma("unroll") for (int kh_ = 0; kh_ < 3; ++kh_)                \
            _Pragma("unroll") for (int r_ = 0; r_ < 4; ++r_)               \
                acc[r_] = __builtin_amdgcn_mfma_i32_32x32x32_i8(           \
                    AW[kh_], BB[r_ + kh_], acc[r_], 0, 0, 0);              \
        __builtin_amdgcn_s_setprio(0);                                     \
    } while (0)

// pipelined step: prefetch (next) then MFMA (cur); sched_barrier keeps the
// MIR schedule from hoisting MFMAs above the prefetch issue point.
#define STEP(AWN, BBN, KWN, C32N, AWC, BBC)                                \
    do {                                                                   \
        LDA(AWN, KWN, C32N);                                               \
        LDB(BBN, KWN, C32N);                                               \
        __builtin_amdgcn_sched_barrier(0);                                 \
        MM(AWC, BBC);                                                      \
        __builtin_amdgcn_sched_barrier(0);                                 \
    } while (0)

// ---- implicit-GEMM conv, i8 MFMA 32x32x32 (best measured: R18/R11 structure) ----
// grid 1792 = 32n x 14hb x 2mh x 2oh ; block 256 thr = 4 waves
// wave g: oc [oh*128+g*32, +32) x 4 rows x 32 cols ; acc = 4 x v16i
template <bool QOUT>
__global__ __launch_bounds__(256, 3) void k_conv(const unsigned char* __restrict__ xin,
                                                 const signed char* __restrict__ wf,
                                                 const float* __restrict__ ep,
                                                 const float* __restrict__ a2p,
                                                 unsigned char* __restrict__ hq,
                                                 float* __restrict__ yout) {
    __shared__ __align__(16) unsigned char sm[ACT_LDS];  // acts; hbuf aliased later
    const int bid = blockIdx.x;
    const int oh = bid & 1;
    const int mh = (bid >> 1) & 1;
    const int hb = (bid >> 2) % 14;
    const int n = (bid >> 2) / 14;
    const int h0 = hb * 4;
    const int mbase = mh * 32;
    const int tid = threadIdx.x;

    // ---- stage 6 act rows x 34 cols: packed global -> UNPACKED u8 LDS ----
    {
        u64 tmp[13];
#pragma unroll
        for (int k = 0; k < 13; ++k) {
            int u = tid + (k << 8);
            u = u > (NSTG - 1) ? (NSTG - 1) : u;
            const int r = u / 544;
            const int rem = u - r * 544;
            const int col = rem >> 4;
            const int t8 = rem & 15;
            int y = h0 - 1 + r;
            int xi = mbase - 1 + col;
            y = y < 0 ? 0 : (y > 55 ? 55 : y);
            xi = xi < 0 ? 0 : (xi > 55 ? 55 : xi);
            tmp[k] = *(const u64*)(xin + ((((size_t)n * Hh + y) * Ww + xi) << 7) + (t8 << 3));
        }
#pragma unroll
        for (int k = 0; k < 13; ++k) {
            const int u = tid + (k << 8);
            if (u < NSTG) {
                const int r = u / 544;
                const int rem = u - r * 544;
                const int col = rem >> 4;
                const int t8 = rem & 15;
                const int y = h0 - 1 + r;
                const int xi = mbase - 1 + col;
                const u64 p = ((unsigned)y < 56u && (unsigned)xi < 56u) ? tmp[k] : 0;
                const u64 lo = p & 0x0F0F0F0F0F0F0F0FULL;
                const u64 hi = (p >> 4) & 0x0F0F0F0F0F0F0F0FULL;
                v4i wv;
                wv[0] = (int)lo;
                wv[1] = (int)(lo >> 32);
                wv[2] = (int)hi;
                wv[3] = (int)(hi >> 32);
                *(v4i*)(sm + r * RSTR + col * 256 + ((t8 ^ (col & 15)) << 4)) = wv;
            }
        }
    }
    __syncthreads();

    const int lane = tid & 63;
    const int g = tid >> 6;
    const int half = lane >> 5;
    const int lm = lane & 31;
    const int octile = oh * 4 + g;
    const int boff = ((bid << 2) | g) & 7;  // per-WAVE stagger

    v16i acc[4] = {};
    const v4i* wpg = (const v4i*)wf + octile * 64 + lane;

    int pkw[3];
#pragma unroll
    for (int kw = 0; kw < 3; ++kw) {
        const int col = lm + kw;  // 0..33, in range
        pkw[kw] = (col * 256) ^ (half << 4) ^ ((col & 15) << 4);
    }

    v4i awA[3], awB[3], bA[6], bB[6];
    // prologue: step 0 = (c32 ord 0, kw 0)
    LDA(awA, 0, boff);
    LDB(bA, 0, boff);

#pragma unroll 1
    for (int s6 = 0; s6 < 24; s6 += 6) {
        const int i0 = s6 / 3;
        const int ca = (i0 + boff) & 7;      // c32 for steps k=0..2
        const int cb = (i0 + 1 + boff) & 7;  // c32 for steps k=3..5
        const int cc = (i0 + 2 + boff) & 7;  // prefetch target after k=5
        STEP(awB, bB, 1, ca, awA, bA);  // k=0: compute (A,kw0,ca); prefetch (B,kw1,ca)
        STEP(awA, bA, 2, ca, awB, bB);  // k=1: compute (B,kw1,ca); prefetch (A,kw2,ca)
        STEP(awB, bB, 0, cb, awA, bA);  // k=2: compute (A,kw2,ca); prefetch (B,kw0,cb)
        STEP(awA, bA, 1, cb, awB, bB);  // k=3: compute (B,kw0,cb); prefetch (A,kw1,cb)
        STEP(awB, bB, 2, cb, awA, bA);  // k=4: compute (A,kw1,cb); prefetch (B,kw2,cb)
        STEP(awA, bA, 0, cc, awB, bB);  // k=5: compute (B,kw2,cb); prefetch (A,kw0,cc)
    }

    // ---- epilogue ----
    if constexpr (QOUT) {
        __syncthreads();  // acts dead; reuse sm as hbuf [4 r][32 w][16 dwords]
        unsigned int* hb = (unsigned int*)sm;
        const float inva = 1.0f / a2p[0];
        const int oc0w = oh * 128 + g * 32;
        const int d0 = 4 * g + half;
#pragma unroll
        for (int r = 0; r < 4; ++r) {
            const v16i av = acc[r];
            unsigned int pk0 = 0, pk1 = 0;
#pragma unroll
            for (int q = 0; q < 4; ++q) {
                const int oc = oc0w + 4 * half + q;
                const unsigned int c0 = (unsigned int)(int)rintf(
                    fminf(fmaxf(fmaf((float)av[q], ep[oc], ep[256 + oc]), 0.f) * inva, 15.f));
                const unsigned int c1 = (unsigned int)(int)rintf(
                    fminf(fmaxf(fmaf((float)av[4 + q], ep[oc + 8], ep[264 + oc]), 0.f) * inva, 15.f));
                const unsigned int c2 = (unsigned int)(int)rintf(
                    fminf(fmaxf(fmaf((float)av[8 + q], ep[oc + 16], ep[272 + oc]), 0.f) * inva, 15.f));
                const unsigned int c3 = (unsigned int)(int)rintf(
                    fminf(fmaxf(fmaf((float)av[12 + q], ep[oc + 24], ep[280 + oc]), 0.f) * inva, 15.f));
                pk0 |= (c0 | (c1 << 4)) << (8 * q);
                pk1 |= (c2 | (c3 << 4)) << (8 * q);
            }
            const int rb = (r * 32 + lm) * 16;
            hb[rb + (d0 ^ (lm & 15))] = pk0;
            hb[rb + ((d0 + 2) ^ (lm & 15))] = pk1;
        }
        __syncthreads();
        unsigned int* dst = (unsigned int*)hq;
        for (int j = tid; j < 4 * 32 * 16; j += 256) {
            const int rw = j >> 4, dw = j & 15;
            const int r = rw >> 5, wl = rw & 31;
            const int w = mbase + wl;
            if (w < 56)
                dst[((size_t)((n * Hh + h0 + r) * Ww) + w) * 32 + oh * 16 + dw] =
                    hb[(rw << 4) + (dw ^ (wl & 15))];
        }
    } else {
        const int w = mbase + lm;
        if (w < 56) {
            float* dst = yout + (size_t)n * Cc * 3136 + (size_t)h0 * 56 + w;
#pragma unroll
            for (int r = 0; r < 4; ++r) {
                const v16i av = acc[r];
#pragma unroll
                for (int reg = 0; reg < 16; ++reg) {
                    const int oc = oh * 128 + g * 32 + (reg & 3) + 8 * (reg >> 2) + 4 * half;
                    dst[(size_t)oc * 3136 + r * 56] =
                        fmaxf(fmaf((float)av[reg], ep[oc], ep[256 + oc]), 0.f);
                }
            }
        }
    }
}

extern "C" void kernel_launch(void* const* d_in, const int* in_sizes, int n_in,
                              void* d_out, int out_size, void* d_ws, size_t ws_size,
                              hipStream_t stream) {
    const float* x = (const float*)d_in[0];
    const float* w1 = (const float*)d_in[1];
    const float* a1 = (const float*)d_in[2];
    const float* g1 = (const float*)d_in[3];
    const float* b1 = (const float*)d_in[4];
    const float* m1 = (const float*)d_in[5];
    const float* v1 = (const float*)d_in[6];
    const float* w2 = (const float*)d_in[7];
    const float* a2 = (const float*)d_in[8];
    const float* g2 = (const float*)d_in[9];
    const float* b2 = (const float*)d_in[10];
    const float* m2 = (const float*)d_in[11];
    const float* v2 = (const float*)d_in[12];

    // workspace (~27.1 MB)
    signed char* wf1 = (signed char*)d_ws;             // 589824 B
    signed char* wf2 = wf1 + 589824;                   // 589824 B
    float* wsc1 = (float*)(wf2 + 589824);              // 256 f
    float* wsc2 = wsc1 + 256;                          // 256 f
    float* ep = wsc2 + 256;                            // 1024 f
    unsigned char* xq1 = (unsigned char*)(ep + 1024);  // 12845056 B (packed NHWC)
    unsigned char* hq = xq1 + (size_t)12845056;        // 12845056 B (packed NHWC)

    k_binpack2<<<512, 256, 0, stream>>>(w1, w2, wf1, wf2, wsc1, wsc2);
    k_prep<<<1, 256, 0, stream>>>(g1, b1, m1, v1, g2, b2, m2, v2, a1, a2, wsc1, wsc2, ep);
    k_quant_nhwc<<<Bn * Hh * 4, 256, 0, stream>>>(x, xq1, a1);

    // layer 1: packed x -> packed h (BN+ReLU+LSQ(alpha2) fused)
    k_conv<true><<<1792, 256, 0, stream>>>(xq1, wf1, ep, a2, hq, nullptr);
    // layer 2: packed h -> fp32 NCHW out (BN+ReLU)
    k_conv<false><<<1792, 256, 0, stream>>>(hq, wf2, ep + 512, nullptr, nullptr, (float*)d_out);
}